// Round 10
// baseline (126.546 us; speedup 1.0000x reference)
//
#include <hip/hip_runtime.h>
#include <stdint.h>

#define BATCH 32
#define H 512
#define W 512
#define NACC 16
#define TH 32              // center rows per tile
#define HALO 9             // need coverage steps a=1..9 only
#define RH (TH + 2*HALO)   // 50 rows incl. halo
#define NWORDS (RH*8)      // 400 mask words per image
#define NT 512
#define NW (NT/64)         // 8 waves
#define NTILE (H/TH)       // 16
#define NBLK (NTILE*BATCH) // 512 blocks = 2/CU

// part[fid*NACC + k] per-block partials (no atomics, deterministic):
//  0: sum(p*g)  1: sum(p)  2: sum(g)
//  3: cnt_pe 4: cnt_pm 5: cnt_pj  6: cnt_ge 7: cnt_gm 8: cnt_gj
//  9: int_e 10: int_m 11: int_j
// 12: dsum_p2g 13: cnt_p2g 14: dsum_g2p 15: cnt_g2p

__global__ __launch_bounds__(NT, 4) void fused_kernel(
    const float* __restrict__ pred, const float* __restrict__ gt,
    float* __restrict__ part)
{
    // single-buffered masks (+1 pad word each end for clamped neighbor reads)
    __shared__ uint64_t MpS[NWORDS + 2];
    __shared__ uint64_t MgS[NWORDS + 2];
    __shared__ float    EC[2][TH];       // pred colsums at cols 255|256
    __shared__ float    red[NW][16];

    uint64_t* Mp = MpS + 1;   // flat index o = row*8 + word
    uint64_t* Mg = MgS + 1;

    // fid = tile*32 + b: vertically-adjacent tiles of one image are 32 apart
    // => same XCD under mod-8 round-robin dispatch (halo rows share L2).
    int fid  = blockIdx.x;
    int b    = fid & 31;
    int tile = fid >> 5;

    const float* pimg = pred + (size_t)b * H * W;
    const float* gimg = gt   + (size_t)b * H * W;
    int y0 = tile * TH;
    int tid = threadIdx.x, lane = tid & 63, wid = tid >> 6;

    // ---- Phase 1: ballot masks, rows y0-9..y0+40 (400 = 25x16, x2 unroll)
    for (int s = wid; s < NWORDS; s += 2 * NW) {
        int sB = s + NW;                         // always < 400
        int ryA = y0 - HALO + (s >> 3);
        int ryB = y0 - HALO + (sB >> 3);
        float vpA = 0.f, vgA = 0.f, vpB = 0.f, vgB = 0.f;
        if ((unsigned)ryA < (unsigned)H) {
            int i0 = ryA * W + (s & 7) * 64 + lane;
            vpA = pimg[i0]; vgA = gimg[i0];
        }
        if ((unsigned)ryB < (unsigned)H) {
            int i1 = ryB * W + (sB & 7) * 64 + lane;
            vpB = pimg[i1]; vgB = gimg[i1];
        }
        unsigned long long mpA = __ballot(vpA > 0.5f);
        unsigned long long mgA = __ballot(vgA > 0.5f);
        unsigned long long mpB = __ballot(vpB > 0.5f);
        unsigned long long mgB = __ballot(vgB > 0.5f);
        if (lane == 0) {
            Mp[s]  = mpA; Mg[s]  = mgA;
            Mp[sB] = mpB; Mg[sB] = mgB;
        }
    }
    if (tid == 0) { MpS[0] = 0; MpS[NWORDS + 1] = 0; MgS[0] = 0; MgS[NWORDS + 1] = 0; }
    // pred edge colsums (cols 255,256) for the cross-wave stencil halo
    if (tid < 2 * TH) {
        int c = tid >> 5, r = tid & (TH - 1);
        int y = y0 + r, col = 255 + c;
        float sum = (y > 0     ? pimg[(size_t)(y - 1) * W + col] : 0.f)
                  +              pimg[(size_t)y * W + col]
                  + (y < H - 1 ? pimg[(size_t)(y + 1) * W + col] : 0.f);
        EC[c][r] = sum;
    }
    __syncthreads();

    // ---- Stencil + dice: pred via floats (rolling rows), gt via bit popcounts
    // 9 classification counters packed into one u64 (7-bit fields, max 32/thr)
    float v0 = 0.f, v1 = 0.f;
    uint64_t cpack = 0ULL;
    {
        int qi = tid & 127, h = tid >> 7;     // h in 0..3, 8 rows each
        int x4 = qi * 4;
        int wdx = qi >> 4;                    // gt word for this quad
        int ss = (qi & 15) * 4;               // bit offset of x4 in word
        int ys = y0 + h * 8;

        auto win6 = [&](int rb) -> uint32_t {
            const uint64_t* row = &Mg[rb * 8];
            uint64_t bm = row[wdx];
            if (ss == 0) {
                uint64_t lo = wdx ? row[wdx - 1] : 0ULL;
                return (uint32_t)(((bm << 1) | (lo >> 63)) & 0x3FULL);
            }
            uint32_t v = (uint32_t)((bm >> (ss - 1)) & 0x3FULL);
            if (ss == 60) {
                uint64_t hi = (wdx < 7) ? row[wdx + 1] : 0ULL;
                v |= ((uint32_t)hi & 1u) << 5;
            }
            return v;
        };

        int rb0 = h * 8 + HALO - 1;           // bit-row of (ys-1)
        uint32_t wU = win6(rb0), wM = win6(rb0 + 1);

        float4 pm4, pc4;
        {
            bool hm = ys > 0;
            pm4 = hm ? *(const float4*)(pimg + (size_t)(ys - 1) * W + x4)
                     : make_float4(0, 0, 0, 0);
            pc4 = *(const float4*)(pimg + (size_t)ys * W + x4);
        }
        for (int r = 0; r < 8; ++r) {
            int y = ys + r;
            float4 pp4 = (y < H - 1) ? *(const float4*)(pimg + (size_t)(y + 1) * W + x4)
                                     : make_float4(0, 0, 0, 0);
            uint32_t wD = win6(rb0 + 2 + r);
            int ry = h * 8 + r;

            float ps[6];
            ps[1] = pm4.x + pc4.x + pp4.x; ps[2] = pm4.y + pc4.y + pp4.y;
            ps[3] = pm4.z + pc4.z + pp4.z; ps[4] = pm4.w + pc4.w + pp4.w;
            float psl = __shfl_up(ps[4], 1, 64);
            float psr = __shfl_down(ps[1], 1, 64);
            if (lane == 0)  psl = (qi == 0)   ? 0.f : EC[0][ry];
            if (lane == 63) psr = (qi == 127) ? 0.f : EC[1][ry];
            ps[0] = psl; ps[5] = psr;

            float pcv[4] = {pc4.x, pc4.y, pc4.z, pc4.w};
            #pragma unroll
            for (int j = 0; j < 4; ++j) {
                float np = ps[j] + ps[j + 1] + ps[j + 2] - pcv[j];
                bool pon = pcv[j] > 0.5f;
                bool pe  = pon && (np == 1.f);
                bool pmb = pon && (np == 2.f);
                bool pjb = pon && (np > 2.f);
                uint32_t n9 = ((wU >> j) & 7u) | (((wM >> j) & 7u) << 3) | (((wD >> j) & 7u) << 6);
                uint32_t cen = (wM >> (j + 1)) & 1u;
                int ng = __popc(n9) - (int)cen;
                bool gon = cen != 0u;
                bool ge  = gon && (ng == 1);
                bool gmb = gon && (ng == 2);
                bool gjb = gon && (ng > 2);
                v1 += pcv[j];
                v0 += gon ? pcv[j] : 0.f;
                cpack += (uint64_t)pe
                       | ((uint64_t)pmb << 7)
                       | ((uint64_t)pjb << 14)
                       | ((uint64_t)ge  << 21)
                       | ((uint64_t)gmb << 28)
                       | ((uint64_t)gjb << 35)
                       | ((uint64_t)(pe  && ge)  << 42)
                       | ((uint64_t)(pmb && gmb) << 49)
                       | ((uint64_t)(pjb && gjb) << 56);
            }
            pm4 = pc4; pc4 = pp4; wU = wM; wM = wD;
        }
    }

    // ---- Distance: barrier-free register dilation.
    // C_a = S_a(V_a), V_a = OR rows rc-a..rc+a. Incremental:
    //   C_a = C_{a-1} | S_{a-1}(N_a) | shift_{+-a}(V_a),  N_a = rows rc+-a.
    // S (symmetric horizontal range-OR) built by exact shift-doubling with
    // neighbor-word carries. Waves 0-3: p2g (T=pred, cover=gt); 4-7: g2p.
    bool isP = tid < 256;
    int idx = tid & 255;
    int o   = (HALO + (idx >> 3)) * 8 + (idx & 7);  // rows rc in [9,40]: rc+-9 in bounds
    int w   = idx & 7;
    bool wL = (w > 0), wR = (w < 7);
    const uint64_t* MT = isP ? Mp : Mg;
    const uint64_t* MV = isP ? Mg : Mp;

    uint64_t T = MT[o];
    int dcnt = __popcll(T);
    int dsum = dcnt;                       // a=0 baseline: every target pixel >= 1
    uint64_t VM = MV[o];
    uint64_t VL = wL ? MV[o - 1] : 0ULL;
    uint64_t VR = wR ? MV[o + 1] : 0ULL;
    uint64_t C = VM;

    #pragma unroll
    for (int a = 1; a <= 9; ++a) {
        int lo = o - 8 * a, hi = o + 8 * a;
        uint64_t NM = MV[lo] | MV[hi];
        uint64_t NL = wL ? (MV[lo - 1] | MV[hi - 1]) : 0ULL;   // lo-1 >= -1: pad word
        uint64_t NR = wR ? (MV[lo + 1] | MV[hi + 1]) : 0ULL;   // hi+1 <= 400: pad word
        // C |= S_{a-1}(N): symmetric range-OR via shift doubling (exact range)
        uint64_t SL = NL, SM = NM, SR = NR;
        const int m = a - 1;
        if (m >= 1) {
            SM |= (SM << 1) | (SM >> 1) | (SL >> 63) | (SR << 63);
            SL |= SL << 1; SR |= SR >> 1;
        }
        if (m >= 2) {
            const int s = (m == 2) ? 1 : 2;
            SM |= (SM << s) | (SM >> s) | (SL >> (64 - s)) | (SR << (64 - s));
            SL |= SL << s; SR |= SR >> s;
        }
        if (m >= 4) {
            const int s = (m - 3 < 4) ? (m - 3) : 4;
            SM |= (SM << s) | (SM >> s) | (SL >> (64 - s)) | (SR << (64 - s));
            SL |= SL << s; SR |= SR >> s;
        }
        if (m >= 8) {
            const int s = m - 7;
            SM |= (SM << s) | (SM >> s) | (SL >> (64 - s)) | (SR << (64 - s));
            SL |= SL << s; SR |= SR >> s;
        }
        C |= SM;
        VL |= NL; VM |= NM; VR |= NR;
        C |= (VM << a) | (VM >> a) | (VL >> (64 - a)) | (VR << (64 - a));
        dsum += __popcll(T & ~C);
    }

    // ---- Reductions -> per-block partials (no atomics)
    float vals[16];
    vals[0] = v0; vals[1] = v1;
    vals[2]  = isP ? 0.f : (float)dcnt;    // sum(g) = popc of gt target words
    vals[3]  = (float)((cpack      ) & 0x7F);
    vals[4]  = (float)((cpack >> 7 ) & 0x7F);
    vals[5]  = (float)((cpack >> 14) & 0x7F);
    vals[6]  = (float)((cpack >> 21) & 0x7F);
    vals[7]  = (float)((cpack >> 28) & 0x7F);
    vals[8]  = (float)((cpack >> 35) & 0x7F);
    vals[9]  = (float)((cpack >> 42) & 0x7F);
    vals[10] = (float)((cpack >> 49) & 0x7F);
    vals[11] = (float)((cpack >> 56) & 0x7F);
    vals[12] = isP ? (float)dsum : 0.f;
    vals[13] = isP ? (float)dcnt : 0.f;
    vals[14] = isP ? 0.f : (float)dsum;
    vals[15] = isP ? 0.f : (float)dcnt;
    #pragma unroll
    for (int j = 0; j < 16; ++j)
        #pragma unroll
        for (int off = 32; off; off >>= 1)
            vals[j] += __shfl_down(vals[j], off, 64);
    if (lane == 0) {
        #pragma unroll
        for (int j = 0; j < 16; ++j) red[wid][j] = vals[j];
    }
    __syncthreads();
    if (tid < 16) {
        float s = 0.f;
        #pragma unroll
        for (int wv = 0; wv < NW; ++wv) s += red[wv][tid];
        part[fid * NACC + tid] = s;
    }
}

// ---------------------------------------------------------------------------
// Final: reduce 512x16 partials -> 32x16 -> scalar. One block, deterministic.
// ---------------------------------------------------------------------------
__global__ __launch_bounds__(512) void final_kernel(
    const float* __restrict__ part, float* __restrict__ out)
{
    __shared__ float sacc[BATCH][NACC];
    __shared__ float tri[BATCH][3];
    int t = threadIdx.x;
    {
        int b = t >> 4, k = t & 15;
        float s = 0.f;
        #pragma unroll 4
        for (int j = 0; j < NTILE; ++j)            // fid = j*32 + b
            s += part[((j << 5) + b) * NACC + k];
        sacc[b][k] = s;
    }
    __syncthreads();
    if (t < BATCH) {
        const float* a = sacc[t];
        float inter = a[0], psum = a[1], gsum = a[2];
        float dice = (2.f * inter + 1.f) / (psum + gsum + 1.f);

        float pe = a[3], pm = a[4], pj = a[5];
        float ge = a[6], gm = a[7], gj = a[8];
        float ie = a[9], im = a[10], ij = a[11];
        float e_iou = (ie + 1.f) / (pe + ge - ie + 1.f);
        float m_iou = (im + 1.f) / (pm + gm - im + 1.f);
        float j_iou = (ij + 1.f) / (pj + gj - ij + 1.f);
        float total = ge + gj + gm + 1.f;
        float sloss = 1.f - ((ge / total) * e_iou + (gj / total) * j_iou + (gm / total) * m_iou);

        float p2g = a[12] / (a[13] + 1.f);
        float g2p = a[14] / (a[15] + 1.f);
        float med = ((p2g + g2p) * 0.5f) / 10.f;
        tri[t][0] = dice; tri[t][1] = sloss; tri[t][2] = med;
    }
    __syncthreads();
    if (t == 0) {
        float dice = 0.f, sloss = 0.f, med = 0.f;
        for (int b = 0; b < BATCH; ++b) {
            dice += tri[b][0]; sloss += tri[b][1]; med += tri[b][2];
        }
        float dice_loss  = 1.f - dice / (float)BATCH;
        float structural = sloss / (float)BATCH;
        float medial     = med / (float)BATCH;
        float avg = (dice_loss + structural + medial) / 3.f;
        float r = dice_loss  / (dice_loss  + 1.f) * avg
                + structural / (structural + 1.f) * avg
                + medial     / (medial     + 1.f) * avg;
        out[0] = r;
    }
}

extern "C" void kernel_launch(void* const* d_in, const int* in_sizes, int n_in,
                              void* d_out, int out_size, void* d_ws, size_t ws_size,
                              hipStream_t stream)
{
    const float* pred = (const float*)d_in[0];
    const float* gt   = (const float*)d_in[1];
    float* part = (float*)d_ws;
    float* out  = (float*)d_out;

    fused_kernel<<<dim3(NBLK), NT, 0, stream>>>(pred, gt, part);
    final_kernel<<<1, 512, 0, stream>>>(part, out);
}